// Round 3
// baseline (139.689 us; speedup 1.0000x reference)
//
#include <hip/hip_runtime.h>
#include <math.h>

// NeuralSplineFourierFilterNNX — tiny MLP on scalar `a` parameterizes a
// degree-3 B-spline; evaluate at 256^3 fp32 grid points.
//
// Kernel 1 (1 block, 64 threads): MLP -> softmax/cumsum knots -> 15 per-segment
//   power-basis cubics in u = x - t_seg (exact divided differences).
// Kernel 2 (2048x256, grid-stride float4): clip, branch-free 14-compare segment
//   count, 1 ds_read_b128 (float4 coeffs) + 1 ds_read_b32 (start), Horner.
//   Nontemporal load/store (streaming, no reuse). Memory-bound ~134 MB.

typedef float fvec4 __attribute__((ext_vector_type(4)));  // clang vector: legal for nontemporal builtins

__device__ __forceinline__ float deboor_eval(float x, int k, const float* t, const float* c) {
    float d[4];
#pragma unroll
    for (int j = 0; j < 4; ++j) d[j] = c[j + k - 3];
#pragma unroll
    for (int r = 1; r <= 3; ++r) {
#pragma unroll
        for (int j = 3; j >= 1; --j) {
            if (j < r) continue;   // constant-folds under unroll
            float tlo = t[j + k - 3];
            float thi = t[j + 1 + k - r];
            float al = (x - tlo) / (thi - tlo);
            d[j] = (1.0f - al) * d[j - 1] + al * d[j];
        }
    }
    return d[3];
}

// ws layout (floats):
//   [0..13]   boundaries b[j] = knot[j+1]  (segment search)
//   [16..30]  segment start = knot[s]
//   [32..91]  float4 coeffs per segment: ws[32+4s .. 32+4s+3] = c0,c1,c2,c3
__global__ void spline_setup_kernel(
    const float* __restrict__ a,  const float* __restrict__ W1, const float* __restrict__ b1,
    const float* __restrict__ W2, const float* __restrict__ b2,
    const float* __restrict__ Ww, const float* __restrict__ bw,
    const float* __restrict__ Wk, const float* __restrict__ bk,
    float* __restrict__ ws)
{
    __shared__ float net1[32], net2[32], cpt[18], kl[15], ak[22];
    int t = threadIdx.x;
    float av = a[0];

    if (t < 32) net1[t] = sinf(av * W1[t] + b1[t]);
    __syncthreads();

    if (t < 32) {
        float s = b2[t];
#pragma unroll
        for (int i = 0; i < 32; ++i) s += net1[i] * W2[i * 32 + t];
        net2[t] = sinf(s);
    }
    __syncthreads();

    if (t < 17) {                     // control points: w = concat([0], net@Ww+bw)
        float s = bw[t];
#pragma unroll
        for (int i = 0; i < 32; ++i) s += net2[i] * Ww[i * 17 + t];
        cpt[t + 1] = s;
    }
    if (t == 63) cpt[0] = 0.0f;
    if (t >= 32 && t < 47) {          // knot logits
        int j = t - 32;
        float s = bk[j];
#pragma unroll
        for (int i = 0; i < 32; ++i) s += net2[i] * Wk[i * 15 + j];
        kl[j] = s;
    }
    __syncthreads();

    if (t == 0) {                     // softmax + cumsum -> padded knot vector ak[22]
        float m = kl[0];
        for (int j = 1; j < 15; ++j) m = fmaxf(m, kl[j]);
        float e[15], sum = 0.0f;
        for (int j = 0; j < 15; ++j) { e[j] = expf(kl[j] - m); sum += e[j]; }
        float inv = 1.0f / sum;
        ak[0] = ak[1] = ak[2] = 0.0f;
        ak[3] = 0.0f;                 // prepended zero knot
        float cum = 0.0f;
        for (int j = 0; j < 15; ++j) { cum += e[j]; ak[4 + j] = cum * inv; }
        ak[19] = ak[20] = ak[21] = 1.0f;
    }
    __syncthreads();

    if (t < 14) ws[t] = ak[4 + t];    // search boundaries: knots 1..14

    if (t < 15) {                     // segment s: knot-index k = s+3, x in [ak[k], ak[k+1])
        int k = t + 3;
        float t0 = ak[k], t1 = ak[k + 1];
        float dl = (t1 - t0) * (1.0f / 3.0f);
        float f0 = deboor_eval(t0,              k, ak, cpt);
        float f1 = deboor_eval(t0 + dl,         k, ak, cpt);
        float f2 = deboor_eval(t0 + 2.0f * dl,  k, ak, cpt);
        float f3 = deboor_eval(t0 + 3.0f * dl,  k, ak, cpt);
        // Newton divided differences (equispaced, spacing dl) -> power basis in u = x - t0
        float idl  = 1.0f / dl;
        float g01  = (f1 - f0) * idl, g12 = (f2 - f1) * idl, g23 = (f3 - f2) * idl;
        float h012 = (g12 - g01) * (0.5f * idl), h123 = (g23 - g12) * (0.5f * idl);
        float q    = (h123 - h012) * (idl * (1.0f / 3.0f));
        float c0 = f0;
        float c1 = g01 - dl * h012 + 2.0f * dl * dl * q;
        float c2 = h012 - 3.0f * dl * q;
        float c3 = q;
        ws[16 + t] = t0;
        ws[32 + 4 * t + 0] = c0;
        ws[32 + 4 * t + 1] = c1;
        ws[32 + 4 * t + 2] = c2;
        ws[32 + 4 * t + 3] = c3;
    }
}

__global__ __launch_bounds__(256) void spline_eval_kernel(
    const float* __restrict__ x, const float* __restrict__ p,
    float* __restrict__ out, int n)
{
    __shared__ float  sStart[16];
    __shared__ fvec4  sC[16];          // 16B-aligned: one ds_read_b128 per point
    int t = threadIdx.x;
    if (t < 15) {
        sStart[t] = p[16 + t];
        sC[t]     = ((const fvec4*)(p + 32))[t];   // p 256B-aligned (d_ws)
    }
    float bb[14];                      // wave-uniform addresses -> scalar regs
#pragma unroll
    for (int j = 0; j < 14; ++j) bb[j] = p[j];
    __syncthreads();

    const float kInvSqrt3 = 0.57735026918962576f;
    const float kXMax     = 1.0f - 1e-4f;

    int n4 = n >> 2;
    int gtid = blockIdx.x * blockDim.x + t;
    int stride = gridDim.x * blockDim.x;
    const fvec4* x4 = (const fvec4*)x;
    fvec4* o4 = (fvec4*)out;

    for (int i = gtid; i < n4; i += stride) {
        fvec4 xv = __builtin_nontemporal_load(&x4[i]);
        float rr[4];
#pragma unroll
        for (int e = 0; e < 4; ++e) {
            float xc = fminf(fmaxf(xv[e] * kInvSqrt3, 0.0f), kXMax);
            int s = 0;
#pragma unroll
            for (int j = 0; j < 14; ++j) s += (xc >= bb[j]) ? 1 : 0;  // searchsorted-right
            fvec4 c = sC[s];           // ds_read_b128
            float u = xc - sStart[s];  // ds_read_b32
            rr[e] = fmaf(fmaf(fmaf(c.w, u, c.z), u, c.y), u, c.x);
        }
        fvec4 r; r.x = rr[0]; r.y = rr[1]; r.z = rr[2]; r.w = rr[3];
        __builtin_nontemporal_store(r, &o4[i]);
    }
    // generic tail (n % 4 != 0); no-op for 256^3
    for (int i = (n4 << 2) + gtid; i < n; i += stride) {
        float xc = fminf(fmaxf(x[i] * kInvSqrt3, 0.0f), kXMax);
        int s = 0;
#pragma unroll
        for (int j = 0; j < 14; ++j) s += (xc >= bb[j]) ? 1 : 0;
        fvec4 c = sC[s];
        float u = xc - sStart[s];
        out[i] = fmaf(fmaf(fmaf(c.w, u, c.z), u, c.y), u, c.x);
    }
}

extern "C" void kernel_launch(void* const* d_in, const int* in_sizes, int n_in,
                              void* d_out, int out_size, void* d_ws, size_t ws_size,
                              hipStream_t stream)
{
    const float* x  = (const float*)d_in[0];
    const float* a  = (const float*)d_in[1];
    const float* W1 = (const float*)d_in[2];
    const float* b1 = (const float*)d_in[3];
    const float* W2 = (const float*)d_in[4];
    const float* b2 = (const float*)d_in[5];
    const float* Ww = (const float*)d_in[6];
    const float* bw = (const float*)d_in[7];
    const float* Wk = (const float*)d_in[8];
    const float* bk = (const float*)d_in[9];
    float* ws  = (float*)d_ws;
    float* out = (float*)d_out;

    spline_setup_kernel<<<1, 64, 0, stream>>>(a, W1, b1, W2, b2, Ww, bw, Wk, bk, ws);
    spline_eval_kernel<<<2048, 256, 0, stream>>>(x, ws, out, out_size);
}

// Round 4
// 138.774 us; speedup vs baseline: 1.0066x; 1.0066x over previous
//
#include <hip/hip_runtime.h>
#include <math.h>

// NeuralSplineFourierFilterNNX — tiny MLP on scalar `a` parameterizes a
// degree-3 B-spline; evaluate at 256^3 fp32 grid points.
//
// SINGLE fused kernel (2048x256): every block redundantly computes the spline
// setup (~2K FLOPs: MLP -> softmax/cumsum knots -> 15 per-segment power-basis
// cubics) in its own LDS, then grid-strides over x with float4 nontemporal
// load/store, branch-free 14-compare segment count, ds_read_b128 coeffs,
// 3-FMA Horner. Removes the 1-block setup kernel (~2-4 us idle-GPU launch),
// the inter-kernel dependency gap, and the d_ws round trip.
// Memory-bound: 134 MB traffic -> ~21 us floor.

typedef float fvec4 __attribute__((ext_vector_type(4)));  // legal for nontemporal builtins

__device__ __forceinline__ float deboor_eval(float x, int k, const float* t, const float* c) {
    float d[4];
#pragma unroll
    for (int j = 0; j < 4; ++j) d[j] = c[j + k - 3];
#pragma unroll
    for (int r = 1; r <= 3; ++r) {
#pragma unroll
        for (int j = 3; j >= 1; --j) {
            if (j < r) continue;   // constant-folds under unroll
            float tlo = t[j + k - 3];
            float thi = t[j + 1 + k - r];
            float al = (x - tlo) / (thi - tlo);
            d[j] = (1.0f - al) * d[j - 1] + al * d[j];
        }
    }
    return d[3];
}

__global__ __launch_bounds__(256) void spline_fused_kernel(
    const float* __restrict__ x,
    const float* __restrict__ a,  const float* __restrict__ W1, const float* __restrict__ b1,
    const float* __restrict__ W2, const float* __restrict__ b2,
    const float* __restrict__ Ww, const float* __restrict__ bw,
    const float* __restrict__ Wk, const float* __restrict__ bk,
    float* __restrict__ out, int n)
{
    // ---- per-block redundant setup (~2K FLOPs, weights ~2.5 KB from L2/L3) ----
    __shared__ float net1[32], net2[32], cpt[18], kl[15], ak[22];
    __shared__ float sBB[14];          // segment-search boundaries: knots 1..14
    __shared__ float sStart[16];       // segment start = knot[s]
    __shared__ fvec4 sC[16];           // c0..c3 per segment (one ds_read_b128)

    int t = threadIdx.x;

    if (t < 32) net1[t] = sinf(a[0] * W1[t] + b1[t]);
    __syncthreads();

    if (t < 32) {
        float s = b2[t];
#pragma unroll
        for (int i = 0; i < 32; ++i) s += net1[i] * W2[i * 32 + t];
        net2[t] = sinf(s);
    }
    __syncthreads();

    if (t < 17) {                      // control points: w = concat([0], net@Ww+bw)
        float s = bw[t];
#pragma unroll
        for (int i = 0; i < 32; ++i) s += net2[i] * Ww[i * 17 + t];
        cpt[t + 1] = s;
    }
    if (t == 63) cpt[0] = 0.0f;
    if (t >= 32 && t < 47) {           // knot logits
        int j = t - 32;
        float s = bk[j];
#pragma unroll
        for (int i = 0; i < 32; ++i) s += net2[i] * Wk[i * 15 + j];
        kl[j] = s;
    }
    __syncthreads();

    if (t == 0) {                      // softmax + cumsum -> padded knot vector ak[22]
        float m = kl[0];
        for (int j = 1; j < 15; ++j) m = fmaxf(m, kl[j]);
        float e[15], sum = 0.0f;
        for (int j = 0; j < 15; ++j) { e[j] = expf(kl[j] - m); sum += e[j]; }
        float inv = 1.0f / sum;
        ak[0] = ak[1] = ak[2] = 0.0f;
        ak[3] = 0.0f;                  // prepended zero knot
        float cum = 0.0f;
        for (int j = 0; j < 15; ++j) { cum += e[j]; ak[4 + j] = cum * inv; }
        ak[19] = ak[20] = ak[21] = 1.0f;
    }
    __syncthreads();

    if (t < 14) sBB[t] = ak[4 + t];
    if (t < 15) {                      // segment s: knot-index k = s+3, x in [ak[k], ak[k+1])
        int k = t + 3;
        float t0 = ak[k], t1 = ak[k + 1];
        float dl = (t1 - t0) * (1.0f / 3.0f);
        float f0 = deboor_eval(t0,              k, ak, cpt);
        float f1 = deboor_eval(t0 + dl,         k, ak, cpt);
        float f2 = deboor_eval(t0 + 2.0f * dl,  k, ak, cpt);
        float f3 = deboor_eval(t0 + 3.0f * dl,  k, ak, cpt);
        // Newton divided differences (equispaced, spacing dl) -> power basis in u = x - t0
        float idl  = 1.0f / dl;
        float g01  = (f1 - f0) * idl, g12 = (f2 - f1) * idl, g23 = (f3 - f2) * idl;
        float h012 = (g12 - g01) * (0.5f * idl), h123 = (g23 - g12) * (0.5f * idl);
        float q    = (h123 - h012) * (idl * (1.0f / 3.0f));
        fvec4 c;
        c.x = f0;                                    // c0
        c.y = g01 - dl * h012 + 2.0f * dl * dl * q;  // c1
        c.z = h012 - 3.0f * dl * q;                  // c2
        c.w = q;                                     // c3
        sStart[t] = t0;
        sC[t] = c;
    }
    __syncthreads();

    // ---- streaming eval (memory-bound) ----
    float bb[14];
#pragma unroll
    for (int j = 0; j < 14; ++j) bb[j] = sBB[j];   // broadcast reads, conflict-free

    const float kInvSqrt3 = 0.57735026918962576f;
    const float kXMax     = 1.0f - 1e-4f;

    int n4 = n >> 2;
    int gtid = blockIdx.x * blockDim.x + t;
    int stride = gridDim.x * blockDim.x;
    const fvec4* x4 = (const fvec4*)x;
    fvec4* o4 = (fvec4*)out;

    for (int i = gtid; i < n4; i += stride) {
        fvec4 xv = __builtin_nontemporal_load(&x4[i]);
        float rr[4];
#pragma unroll
        for (int e = 0; e < 4; ++e) {
            float xc = fminf(fmaxf(xv[e] * kInvSqrt3, 0.0f), kXMax);
            int s = 0;
#pragma unroll
            for (int j = 0; j < 14; ++j) s += (xc >= bb[j]) ? 1 : 0;  // searchsorted-right
            fvec4 c = sC[s];            // ds_read_b128
            float u = xc - sStart[s];   // ds_read_b32
            rr[e] = fmaf(fmaf(fmaf(c.w, u, c.z), u, c.y), u, c.x);
        }
        fvec4 r; r.x = rr[0]; r.y = rr[1]; r.z = rr[2]; r.w = rr[3];
        __builtin_nontemporal_store(r, &o4[i]);
    }
    // generic tail (n % 4 != 0); no-op for 256^3
    for (int i = (n4 << 2) + gtid; i < n; i += stride) {
        float xc = fminf(fmaxf(x[i] * kInvSqrt3, 0.0f), kXMax);
        int s = 0;
#pragma unroll
        for (int j = 0; j < 14; ++j) s += (xc >= bb[j]) ? 1 : 0;
        fvec4 c = sC[s];
        float u = xc - sStart[s];
        out[i] = fmaf(fmaf(fmaf(c.w, u, c.z), u, c.y), u, c.x);
    }
}

extern "C" void kernel_launch(void* const* d_in, const int* in_sizes, int n_in,
                              void* d_out, int out_size, void* d_ws, size_t ws_size,
                              hipStream_t stream)
{
    const float* x  = (const float*)d_in[0];
    const float* a  = (const float*)d_in[1];
    const float* W1 = (const float*)d_in[2];
    const float* b1 = (const float*)d_in[3];
    const float* W2 = (const float*)d_in[4];
    const float* b2 = (const float*)d_in[5];
    const float* Ww = (const float*)d_in[6];
    const float* bw = (const float*)d_in[7];
    const float* Wk = (const float*)d_in[8];
    const float* bk = (const float*)d_in[9];
    float* out = (float*)d_out;

    spline_fused_kernel<<<2048, 256, 0, stream>>>(
        x, a, W1, b1, W2, b2, Ww, bw, Wk, bk, out, out_size);
}